// Round 4
// baseline (302.499 us; speedup 1.0000x reference)
//
#include <hip/hip_runtime.h>
#include <hip/hip_bf16.h>
#include <cstdint>
#include <cstddef>

// x[1024][512] f32, hidden_w[19200][512] f32, hidden_b[19200] f32,
// out_w[10][19200] f32, out_b[80][10] f32, neuron_model_id[19200] i32
// (deterministic; recomputed on device). out[1024][80][10] f32.

typedef unsigned short u16;
typedef unsigned int u32;
typedef __bf16 bf16x8 __attribute__((ext_vector_type(8)));
typedef float f32x4 __attribute__((ext_vector_type(4)));

__device__ __forceinline__ u16 f2bf(float f) {
  u32 u = __builtin_bit_cast(u32, f);
  u += 0x7fffu + ((u >> 16) & 1u);   // RNE
  return (u16)(u >> 16);
}

__device__ __forceinline__ void async16(void* l, const void* g) {
  __builtin_amdgcn_global_load_lds(
      (__attribute__((address_space(1))) void*)(void*)g,
      (__attribute__((address_space(3))) void*)l, 16, 0, 0);
}

// ---------------- kernel 0: fp32 -> bf16 convert (x and hidden_w) ------------
__global__ __launch_bounds__(256) void cvt_kernel(
    const float4* __restrict__ xs, uint2* __restrict__ xd, int nx4,
    const float4* __restrict__ ws, uint2* __restrict__ wd, int nw4) {
  int i = blockIdx.x * blockDim.x + threadIdx.x;
  if (i >= nx4 + nw4) return;
  const float4* s; uint2* d; int j;
  if (i < nx4) { s = xs; d = xd; j = i; }
  else         { s = ws; d = wd; j = i - nx4; }
  float4 f = s[j];
  uint2 o;
  o.x = (u32)f2bf(f.x) | ((u32)f2bf(f.y) << 16);
  o.y = (u32)f2bf(f.z) | ((u32)f2bf(f.w) << 16);
  d[j] = o;
}

// ---------------- kernel 1: out = out_b broadcast ----------------------------
__global__ __launch_bounds__(256) void init_out_kernel(
    const float* __restrict__ ob, float* __restrict__ out) {
  int i = blockIdx.x * 256 + threadIdx.x;  // 819200 = 3200*256
  out[i] = ob[i % 800];
}

// ---------------- kernel 2: bf16 GEMM + activation + fused out-projection ----
// 128x128 tile, BK=32, 4 waves (2x2 of 64x64), double-buffered 32KB LDS.
// At 64B row stride the wave's ds_read_b128 pattern covers 64 distinct 16B
// chunks of a 1KB window -> conflict-free without swizzle (linear staging).
// Epilogue: bias+activation in f32, then per-o reduce (4 fma + shfl_xor tree)
// and atomicAdd partials into out (pre-initialized with out_b).
__global__ __launch_bounds__(256, 3) void gemm_fused_kernel(
    const u16* __restrict__ A,     // [1024][512] bf16
    const u16* __restrict__ Bw,    // [19200][512] bf16
    const float* __restrict__ hbias,
    const float* __restrict__ ow,  // [10][19200]
    float* __restrict__ out) {     // [1024][80][10], pre-initialized to out_b
  __shared__ char lds[32768];  // A0@0 A1@8192 B0@16384 B1@24576
  const int t = threadIdx.x;
  const int lane = t & 63;
  const int w = t >> 6;
  // by fast-varying: the 8 blocks sharing a B-tile dispatch to the 8 XCDs
  // at the same time -> B fetched from HBM once, L3 serves the rest.
  const int by = blockIdx.x & 7;
  const int bx = blockIdx.x >> 3;
  const int row0 = by * 128, col0 = bx * 128;
  const int wr = w >> 1, wc = w & 1;

  f32x4 acc[4][4];
#pragma unroll
  for (int m = 0; m < 4; ++m)
#pragma unroll
    for (int n = 0; n < 4; ++n)
#pragma unroll
      for (int r = 0; r < 4; ++r) acc[m][n][r] = 0.f;

  const int srow = lane >> 2;  // row within 16-row chunk
  const int sk8 = lane & 3;    // 16B chunk within 64B row

  auto stage = [&](int buf, int kt) {
    const int k0 = kt * 32 + sk8 * 8;
#pragma unroll
    for (int j = 0; j < 2; ++j) {
      int row = j * 64 + w * 16 + srow;
      async16(lds + buf * 8192 + j * 4096 + w * 1024,
              A + (size_t)(row0 + row) * 512 + k0);
      async16(lds + 16384 + buf * 8192 + j * 4096 + w * 1024,
              Bw + (size_t)(col0 + row) * 512 + k0);
    }
  };

  const int il = lane & 15, q = lane >> 4;

  auto compute = [&](int buf) {
    const char* bA = lds + buf * 8192;
    const char* bB = lds + 16384 + buf * 8192;
    bf16x8 av[4], bv[4];
#pragma unroll
    for (int m = 0; m < 4; ++m)
      av[m] = *(const bf16x8*)(bA + (wr * 64 + m * 16 + il) * 64 + q * 16);
#pragma unroll
    for (int n = 0; n < 4; ++n)
      bv[n] = *(const bf16x8*)(bB + (wc * 64 + n * 16 + il) * 64 + q * 16);
#pragma unroll
    for (int m = 0; m < 4; ++m)
#pragma unroll
      for (int n = 0; n < 4; ++n)
        acc[m][n] = __builtin_amdgcn_mfma_f32_16x16x32_bf16(av[m], bv[n],
                                                            acc[m][n], 0, 0, 0);
  };

  stage(0, 0);
  __syncthreads();
  for (int kt = 0; kt < 16; ++kt) {
    int cur = kt & 1;
    if (kt < 15) stage(cur ^ 1, kt + 1);
    compute(cur);
    __syncthreads();
  }

  // ---- epilogue ----
  // This wave's 64-col half is model-aligned (all boundaries are mult. of 64).
  const int colb = col0 + wc * 64;        // wave-uniform
  const int actid = colb / 4800;          // 0:relu 1:tanh 2:sigmoid 3:gelu
  const int ch = colb % 4800;
  const int rep = ch / 960, cc = ch % 960;
  const int sid = cc < 64 ? 0 : cc < 192 ? 1 : cc < 448 ? 2 : 3;
  const int m_id = actid * 20 + rep * 4 + sid;

  int cols[4]; float bias[4];
#pragma unroll
  for (int n = 0; n < 4; ++n) {
    cols[n] = colb + n * 16 + il;
    bias[n] = hbias[cols[n]];
  }

  // bias + activation, in place, f32
#pragma unroll
  for (int m = 0; m < 4; ++m)
#pragma unroll
    for (int n = 0; n < 4; ++n)
#pragma unroll
      for (int r = 0; r < 4; ++r) {
        float v = acc[m][n][r] + bias[n];
        float o;
        if (actid == 0)      o = fmaxf(v, 0.f);
        else if (actid == 1) o = tanhf(v);
        else if (actid == 2) o = 1.f / (1.f + __expf(-v));
        else                 o = 0.5f * v * (1.f + erff(v * 0.70710678118f));
        acc[m][n][r] = o;
      }

  // fused out-projection: out[b][m_id][o] += sum_h act[b][h] * ow[o][h]
  const int obase = (row0 + wr * 64 + q * 4) * 800 + m_id * 10;
#pragma unroll
  for (int o = 0; o < 10; ++o) {
    float wv[4];
#pragma unroll
    for (int n = 0; n < 4; ++n) wv[n] = ow[o * 19200 + cols[n]];
    float p[16];
#pragma unroll
    for (int m = 0; m < 4; ++m)
#pragma unroll
      for (int r = 0; r < 4; ++r)
        p[m * 4 + r] = acc[m][0][r] * wv[0] + acc[m][1][r] * wv[1]
                     + acc[m][2][r] * wv[2] + acc[m][3][r] * wv[3];
    // reduce over the 16 il-lanes (butterfly; all lanes end with the sum)
#pragma unroll
    for (int mask = 1; mask <= 8; mask <<= 1)
#pragma unroll
      for (int i = 0; i < 16; ++i)
        p[i] += __shfl_xor(p[i], mask);
    if (il == o) {
#pragma unroll
      for (int m = 0; m < 4; ++m)
#pragma unroll
        for (int r = 0; r < 4; ++r)
          atomicAdd(&out[obase + m * 16 * 800 + r * 800 + o], p[m * 4 + r]);
    }
  }
}

extern "C" void kernel_launch(void* const* d_in, const int* in_sizes, int n_in,
                              void* d_out, int out_size, void* d_ws, size_t ws_size,
                              hipStream_t stream) {
  const float* x = (const float*)d_in[0];
  const float* hw = (const float*)d_in[1];
  const float* hb = (const float*)d_in[2];
  const float* ow = (const float*)d_in[3];
  const float* ob = (const float*)d_in[4];
  float* out = (float*)d_out;

  // workspace: x_bf16 (1 MB) | w_bf16 (19.66 MB)
  char* ws = (char*)d_ws;
  u16* xb = (u16*)ws;
  u16* wb = (u16*)(ws + 1048576);

  const int nx4 = (1024 * 512) / 4;    // 131072
  const int nw4 = (19200 * 512) / 4;   // 2457600
  const int tot = nx4 + nw4;           // 2588672 = 10112*256
  cvt_kernel<<<tot / 256, 256, 0, stream>>>((const float4*)x, (uint2*)xb, nx4,
                                            (const float4*)hw, (uint2*)wb, nw4);
  init_out_kernel<<<3200, 256, 0, stream>>>(ob, out);
  gemm_fused_kernel<<<1200, 256, 0, stream>>>(xb, wb, hb, ow, out);
}

// Round 7
// 182.561 us; speedup vs baseline: 1.6570x; 1.6570x over previous
//
#include <hip/hip_runtime.h>
#include <hip/hip_bf16.h>
#include <cstdint>
#include <cstddef>

// x[1024][512] f32, hidden_w[19200][512] f32, hidden_b[19200] f32,
// out_w[10][19200] f32, out_b[80][10] f32, neuron_model_id[19200] i32
// (deterministic; recomputed on device). out[1024][80][10] f32.

typedef unsigned short u16;
typedef unsigned int u32;
typedef __bf16 bf16x8 __attribute__((ext_vector_type(8)));
typedef float f32x4 __attribute__((ext_vector_type(4)));

__device__ __forceinline__ u16 f2bf(float f) {
  u32 u = __builtin_bit_cast(u32, f);
  u += 0x7fffu + ((u >> 16) & 1u);   // RNE
  return (u16)(u >> 16);
}

__device__ __forceinline__ void async16(void* l, const void* g) {
  __builtin_amdgcn_global_load_lds(
      (__attribute__((address_space(1))) void*)(void*)g,
      (__attribute__((address_space(3))) void*)l, 16, 0, 0);
}

// Explicit drain of the global_load_lds queue. The compiler is supposed to
// emit s_waitcnt vmcnt(0) before s_barrier anyway; this makes it unconditional
// (defends against any replay-path edge case with in-flight LDS-DMA).
__device__ __forceinline__ void drain_vm() {
  asm volatile("s_waitcnt vmcnt(0)" ::: "memory");
}

// ---------------- kernel 0: fp32 -> bf16 convert (x and hidden_w) ------------
__global__ __launch_bounds__(256) void cvt_kernel(
    const float4* __restrict__ xs, uint2* __restrict__ xd, int nx4,
    const float4* __restrict__ ws, uint2* __restrict__ wd, int nw4) {
  int i = blockIdx.x * blockDim.x + threadIdx.x;
  if (i >= nx4 + nw4) return;
  const float4* s; uint2* d; int j;
  if (i < nx4) { s = xs; d = xd; j = i; }
  else         { s = ws; d = wd; j = i - nx4; }
  float4 f = s[j];
  uint2 o;
  o.x = (u32)f2bf(f.x) | ((u32)f2bf(f.y) << 16);
  o.y = (u32)f2bf(f.z) | ((u32)f2bf(f.w) << 16);
  d[j] = o;
}

// ---------------- kernel 1: bf16 GEMM (x @ W^T + b) with fused activation ----
// 128x128 tile, BK=64, 4 waves (2x2 of 64x64), double-buffered 64KB LDS.
// 128B-row LDS layout: measured ZERO bank conflicts (round 1); the 64B-row
// BK=32 variant measured 2.4M — keep 128B rows.
// XCD-chunked swizzle: default blockIdx->XCD is round-robin (%8), so blocks
// with blockIdx === c (mod 8) share XCD c's L2. L = c*150 + blockIdx/8 gives
// each XCD a contiguous logical range; by=L%8 nests the 8 M-tiles of one
// B-panel on ONE XCD -> B fetched into that L2 once, A (2 MB) L2-resident.
__global__ __launch_bounds__(256, 2) void gemm_act_kernel(
    const u16* __restrict__ A,
    const u16* __restrict__ Bw,
    const float* __restrict__ hbias,
    u16* __restrict__ aout) {
  __shared__ char lds[65536];  // A: 2 x 16KB, B: 2 x 16KB
  const int t = threadIdx.x;
  const int lane = t & 63;
  const int w = t >> 6;
  const int c = blockIdx.x & 7;
  const int L = c * 150 + (blockIdx.x >> 3);
  const int bx = L >> 3;            // N tile 0..149
  const int by = L & 7;             // M tile 0..7
  const int row0 = by * 128;
  const int col0 = bx * 128;
  const int wr = w >> 1, wc = w & 1;

  f32x4 acc[4][4];
#pragma unroll
  for (int m = 0; m < 4; ++m)
#pragma unroll
    for (int n = 0; n < 4; ++n)
#pragma unroll
      for (int r = 0; r < 4; ++r) acc[m][n][r] = 0.f;

  const int srow = t >> 3;  // 0..31
  const int sc8 = t & 7;    // 16B chunk within 128B row

  auto stage = [&](int buf, int kt) {
    const int k0 = kt * 64 + sc8 * 8;
#pragma unroll
    for (int i = 0; i < 4; ++i) {
      int row = i * 32 + srow;
      async16(lds + buf * 16384 + i * 4096 + w * 1024,
              A + (size_t)(row0 + row) * 512 + k0);
      async16(lds + 32768 + buf * 16384 + i * 4096 + w * 1024,
              Bw + (size_t)(col0 + row) * 512 + k0);
    }
  };

  const int il = lane & 15, q = lane >> 4;

  auto compute = [&](int buf) {
    const char* bA = lds + buf * 16384;
    const char* bB = lds + 32768 + buf * 16384;
#pragma unroll
    for (int ks = 0; ks < 2; ++ks) {
      bf16x8 av[4], bv[4];
#pragma unroll
      for (int m = 0; m < 4; ++m)
        av[m] = *(const bf16x8*)(bA + (wr * 64 + m * 16 + il) * 128 + ks * 64 + q * 16);
#pragma unroll
      for (int n = 0; n < 4; ++n)
        bv[n] = *(const bf16x8*)(bB + (wc * 64 + n * 16 + il) * 128 + ks * 64 + q * 16);
#pragma unroll
      for (int m = 0; m < 4; ++m)
#pragma unroll
        for (int n = 0; n < 4; ++n)
          acc[m][n] = __builtin_amdgcn_mfma_f32_16x16x32_bf16(av[m], bv[n],
                                                              acc[m][n], 0, 0, 0);
    }
  };

  stage(0, 0);
  drain_vm();
  __syncthreads();
  for (int kt = 0; kt < 8; ++kt) {
    int cur = kt & 1;
    if (kt < 7) stage(cur ^ 1, kt + 1);
    compute(cur);
    drain_vm();          // all in-flight LDS-DMA landed before anyone proceeds
    __syncthreads();
  }

  // epilogue: bias + activation (uniform per 16-wide fragment: 4800 % 16 == 0)
#pragma unroll
  for (int n = 0; n < 4; ++n) {
    int gcol = col0 + wc * 64 + n * 16 + il;
    int act = gcol / 4800;  // 0:relu 1:tanh 2:sigmoid 3:gelu(exact)
    float bias = hbias[gcol];
#pragma unroll
    for (int m = 0; m < 4; ++m) {
      int growb = row0 + wr * 64 + m * 16 + q * 4;
#pragma unroll
      for (int r = 0; r < 4; ++r) {
        float v = acc[m][n][r] + bias;
        float o;
        if (act == 0)      o = fmaxf(v, 0.f);
        else if (act == 1) o = tanhf(v);
        else if (act == 2) o = 1.f / (1.f + __expf(-v));
        else               o = 0.5f * v * (1.f + erff(v * 0.70710678118f));
        aout[(size_t)(growb + r) * 19200 + gcol] = f2bf(o);
      }
    }
  }
}

// ---------------- kernel 2: ragged out-projection via MFMA -------------------
// Per block: one model x 64 batch rows (4 waves x 16 rows). Per wave:
// out[16b x 10o] = sum_k a[b][k] * ow[o][k] via mfma_f32_16x16x32_bf16.
// A-frag: lane(il,q) reads a[b0+il][seg0 + k0 + q*8 ..+7] (16B) — 16 x 64B
// contiguous segments per wave -> coalesced; each (b,h) read exactly once.
// B-frag: ow rows (f32, L2-resident) converted to bf16 on the fly.
// MFMA does the k-reduction in hardware: no shuffles, no atomics.
__global__ __launch_bounds__(256) void layer2_kernel(
    const u16* __restrict__ a,    // [1024][19200] bf16
    const float* __restrict__ ow, // [10][19200] f32
    const float* __restrict__ ob, // [80][10] f32
    float* __restrict__ out) {    // [1024][80][10] f32
  const int t = threadIdx.x;
  const int lane = t & 63;
  const int w = t >> 6;
  const int m = blockIdx.x % 80;   // model (interleaved for load balance)
  const int bt = blockIdx.x / 80;  // batch tile 0..15
  const int b0 = bt * 64 + w * 16;
  const int s = m & 3;
  const int rep = (m >> 2) % 5;
  const int act = m / 20;
  const int seg0 = act * 4800 + rep * 960 + 64 * ((1 << s) - 1);
  const int K = 64 << s;
  const int il = lane & 15, q = lane >> 4;

  f32x4 acc = {0.f, 0.f, 0.f, 0.f};
  const u16* arow = a + (size_t)(b0 + il) * 19200 + seg0 + q * 8;
  const float* wrow = ow + il * 19200 + seg0 + q * 8;  // deref only when il<10
  const bool wvalid = il < 10;

  for (int k0 = 0; k0 < K; k0 += 32) {
    bf16x8 af = *(const bf16x8*)(arow + k0);
    union { bf16x8 v; u16 u[8]; } bb;
    if (wvalid) {
      float4 f0 = *(const float4*)(wrow + k0);
      float4 f1 = *(const float4*)(wrow + k0 + 4);
      bb.u[0] = f2bf(f0.x); bb.u[1] = f2bf(f0.y);
      bb.u[2] = f2bf(f0.z); bb.u[3] = f2bf(f0.w);
      bb.u[4] = f2bf(f1.x); bb.u[5] = f2bf(f1.y);
      bb.u[6] = f2bf(f1.z); bb.u[7] = f2bf(f1.w);
    } else {
#pragma unroll
      for (int j = 0; j < 8; ++j) bb.u[j] = 0;
    }
    acc = __builtin_amdgcn_mfma_f32_16x16x32_bf16(af, bb.v, acc, 0, 0, 0);
  }

  if (il < 10) {
    float bias = ob[m * 10 + il];
#pragma unroll
    for (int r = 0; r < 4; ++r)
      out[(size_t)(b0 + q * 4 + r) * 800 + m * 10 + il] = acc[r] + bias;
  }
}

extern "C" void kernel_launch(void* const* d_in, const int* in_sizes, int n_in,
                              void* d_out, int out_size, void* d_ws, size_t ws_size,
                              hipStream_t stream) {
  const float* x = (const float*)d_in[0];
  const float* hw = (const float*)d_in[1];
  const float* hb = (const float*)d_in[2];
  const float* ow = (const float*)d_in[3];
  const float* ob = (const float*)d_in[4];
  float* out = (float*)d_out;

  // workspace layout: x_bf16 (1 MB) | w_bf16 (19.66 MB) | a_bf16 (39.32 MB)
  char* ws = (char*)d_ws;
  u16* xb = (u16*)ws;
  u16* wb = (u16*)(ws + 1048576);
  u16* ab = (u16*)(ws + 1048576 + 19660800);

  const int nx4 = (1024 * 512) / 4;    // 131072
  const int nw4 = (19200 * 512) / 4;   // 2457600
  const int tot = nx4 + nw4;           // 2588672 = 10112*256
  cvt_kernel<<<tot / 256, 256, 0, stream>>>((const float4*)x, (uint2*)xb, nx4,
                                            (const float4*)hw, (uint2*)wb, nw4);
  gemm_act_kernel<<<1200, 256, 0, stream>>>(xb, wb, hb, ab);
  layer2_kernel<<<1280, 256, 0, stream>>>(ab, ow, ob, out);
}

// Round 10
// 177.012 us; speedup vs baseline: 1.7089x; 1.0313x over previous
//
#include <hip/hip_runtime.h>
#include <hip/hip_bf16.h>
#include <cstdint>
#include <cstddef>

// x[1024][512] f32, hidden_w[19200][512] f32, hidden_b[19200] f32,
// out_w[10][19200] f32, out_b[80][10] f32, neuron_model_id[19200] i32
// (deterministic; recomputed on device). out[1024][80][10] f32.

typedef unsigned short u16;
typedef unsigned int u32;
typedef __bf16 bf16x8 __attribute__((ext_vector_type(8)));
typedef float f32x4 __attribute__((ext_vector_type(4)));

__device__ __forceinline__ u16 f2bf(float f) {
  u32 u = __builtin_bit_cast(u32, f);
  u += 0x7fffu + ((u >> 16) & 1u);   // RNE
  return (u16)(u >> 16);
}

__device__ __forceinline__ void async16(void* l, const void* g) {
  __builtin_amdgcn_global_load_lds(
      (__attribute__((address_space(1))) void*)(void*)g,
      (__attribute__((address_space(3))) void*)l, 16, 0, 0);
}

// ---------------- kernel 0: fp32 -> bf16 convert (x and hidden_w) ------------
__global__ __launch_bounds__(256) void cvt_kernel(
    const float4* __restrict__ xs, uint2* __restrict__ xd, int nx4,
    const float4* __restrict__ ws, uint2* __restrict__ wd, int nw4) {
  int i = blockIdx.x * blockDim.x + threadIdx.x;
  if (i >= nx4 + nw4) return;
  const float4* s; uint2* d; int j;
  if (i < nx4) { s = xs; d = xd; j = i; }
  else         { s = ws; d = wd; j = i - nx4; }
  float4 f = s[j];
  uint2 o;
  o.x = (u32)f2bf(f.x) | ((u32)f2bf(f.y) << 16);
  o.y = (u32)f2bf(f.z) | ((u32)f2bf(f.w) << 16);
  d[j] = o;
}

// ---------------- kernel 1: bf16 GEMM (x @ W^T + b) with fused activation ----
// 128x128 tile, BK=64, 4 waves (2x2 of 64x64), double-buffered 64KB LDS.
// XOR swizzle (round-1-verified): source chunk c8 = sc8 ^ (row&7), linear LDS
// dest, read byte ^ ((row&7)<<4). Quarter-wave then covers all 32 banks at
// 2-way (free) aliasing -> measured 0 conflicts in round 1.
// XCD-chunked block mapping (round-7-verified: FETCH 82->18 MB).
// T4 counted-vmcnt pipeline: 3 K-tiles in flight, raw s_barrier, never drain
// vmcnt to 0 in the main loop (explicit waits -> no reliance on compiler).
__global__ __launch_bounds__(256, 2) void gemm_act_kernel(
    const u16* __restrict__ A,
    const u16* __restrict__ Bw,
    const float* __restrict__ hbias,
    u16* __restrict__ aout) {
  __shared__ char lds[65536];  // A: 2 x 16KB, B: 2 x 16KB
  const int t = threadIdx.x;
  const int lane = t & 63;
  const int w = t >> 6;
  const int c = blockIdx.x & 7;
  const int L = c * 150 + (blockIdx.x >> 3);
  const int bx = L >> 3;            // N tile 0..149
  const int by = L & 7;             // M tile 0..7
  const int row0 = by * 128;
  const int col0 = bx * 128;
  const int wr = w >> 1, wc = w & 1;

  f32x4 acc[4][4];
#pragma unroll
  for (int m = 0; m < 4; ++m)
#pragma unroll
    for (int n = 0; n < 4; ++n)
#pragma unroll
      for (int r = 0; r < 4; ++r) acc[m][n][r] = 0.f;

  const int srow = t >> 3;  // 0..31 (row&7 == srow&7 for all staged rows)
  const int sc8 = t & 7;    // 16B chunk within 128B row

  auto stage = [&](int buf, int kt) {
    const int c8 = sc8 ^ (srow & 7);            // inverse-swizzled source
    const int k0 = kt * 64 + c8 * 8;
#pragma unroll
    for (int i = 0; i < 4; ++i) {
      int row = i * 32 + srow;
      async16(lds + buf * 16384 + i * 4096 + w * 1024,
              A + (size_t)(row0 + row) * 512 + k0);
      async16(lds + 32768 + buf * 16384 + i * 4096 + w * 1024,
              Bw + (size_t)(col0 + row) * 512 + k0);
    }
  };

  const int il = lane & 15, q = lane >> 4;

  auto compute = [&](int buf) {
    const char* bA = lds + buf * 16384;
    const char* bB = lds + 32768 + buf * 16384;
#pragma unroll
    for (int ks = 0; ks < 2; ++ks) {
      bf16x8 av[4], bv[4];
#pragma unroll
      for (int m = 0; m < 4; ++m) {
        int row = wr * 64 + m * 16 + il;
        av[m] = *(const bf16x8*)(bA + row * 128 +
                                 ((ks * 64 + q * 16) ^ ((row & 7) << 4)));
      }
#pragma unroll
      for (int n = 0; n < 4; ++n) {
        int row = wc * 64 + n * 16 + il;
        bv[n] = *(const bf16x8*)(bB + row * 128 +
                                 ((ks * 64 + q * 16) ^ ((row & 7) << 4)));
      }
#pragma unroll
      for (int m = 0; m < 4; ++m)
#pragma unroll
        for (int n = 0; n < 4; ++n)
          acc[m][n] = __builtin_amdgcn_mfma_f32_16x16x32_bf16(av[m], bv[n],
                                                              acc[m][n], 0, 0, 0);
    }
  };

  // Pipeline: tiles kt and kt+1 in flight entering iteration kt.
  stage(0, 0);   // 8 loads
  stage(1, 1);   // 8 loads (16 outstanding)
#pragma unroll
  for (int kt = 0; kt < 8; ++kt) {
    if (kt < 7) asm volatile("s_waitcnt vmcnt(8)" ::: "memory");  // cur landed
    else        asm volatile("s_waitcnt vmcnt(0)" ::: "memory");  // last tile
    __builtin_amdgcn_s_barrier();      // all waves' cur loads visible
    compute(kt & 1);
    asm volatile("" ::: "memory");
    __builtin_amdgcn_s_barrier();      // all waves done reading cur
    if (kt < 6) stage(kt & 1, kt + 2); // refill cur's buffer with tile kt+2
  }

  // epilogue: bias + activation (uniform per 16-wide fragment: 4800 % 16 == 0)
#pragma unroll
  for (int n = 0; n < 4; ++n) {
    int gcol = col0 + wc * 64 + n * 16 + il;
    int act = gcol / 4800;  // 0:relu 1:tanh 2:sigmoid 3:gelu(exact)
    float bias = hbias[gcol];
#pragma unroll
    for (int m = 0; m < 4; ++m) {
      int growb = row0 + wr * 64 + m * 16 + q * 4;
#pragma unroll
      for (int r = 0; r < 4; ++r) {
        float v = acc[m][n][r] + bias;
        float o;
        if (act == 0)      o = fmaxf(v, 0.f);
        else if (act == 1) {                      // tanh via hw exp
          float e = __expf(-2.f * fabsf(v));
          o = copysignf((1.f - e) / (1.f + e), v);
        }
        else if (act == 2) o = 1.f / (1.f + __expf(-v));
        else               o = 0.5f * v * (1.f + erff(v * 0.70710678118f));
        aout[(size_t)(growb + r) * 19200 + gcol] = f2bf(o);
      }
    }
  }
}

// ---------------- kernel 2: ragged out-projection via MFMA -------------------
// Per block: one model x 64 batch rows (4 waves x 16 rows). Per wave:
// out[16b x 10o] = sum_k a[b][k] * ow[o][k] via mfma_f32_16x16x32_bf16.
// MFMA does the k-reduction in hardware: no shuffles, no atomics.
__global__ __launch_bounds__(256) void layer2_kernel(
    const u16* __restrict__ a,    // [1024][19200] bf16
    const float* __restrict__ ow, // [10][19200] f32
    const float* __restrict__ ob, // [80][10] f32
    float* __restrict__ out) {    // [1024][80][10] f32
  const int t = threadIdx.x;
  const int lane = t & 63;
  const int w = t >> 6;
  const int m = blockIdx.x % 80;   // model (interleaved for load balance)
  const int bt = blockIdx.x / 80;  // batch tile 0..15
  const int b0 = bt * 64 + w * 16;
  const int s = m & 3;
  const int rep = (m >> 2) % 5;
  const int act = m / 20;
  const int seg0 = act * 4800 + rep * 960 + 64 * ((1 << s) - 1);
  const int K = 64 << s;
  const int il = lane & 15, q = lane >> 4;

  f32x4 acc = {0.f, 0.f, 0.f, 0.f};
  const u16* arow = a + (size_t)(b0 + il) * 19200 + seg0 + q * 8;
  const float* wrow = ow + il * 19200 + seg0 + q * 8;  // deref only when il<10
  const bool wvalid = il < 10;

  for (int k0 = 0; k0 < K; k0 += 32) {
    bf16x8 af = *(const bf16x8*)(arow + k0);
    union { bf16x8 v; u16 u[8]; } bb;
    if (wvalid) {
      float4 f0 = *(const float4*)(wrow + k0);
      float4 f1 = *(const float4*)(wrow + k0 + 4);
      bb.u[0] = f2bf(f0.x); bb.u[1] = f2bf(f0.y);
      bb.u[2] = f2bf(f0.z); bb.u[3] = f2bf(f0.w);
      bb.u[4] = f2bf(f1.x); bb.u[5] = f2bf(f1.y);
      bb.u[6] = f2bf(f1.z); bb.u[7] = f2bf(f1.w);
    } else {
#pragma unroll
      for (int j = 0; j < 8; ++j) bb.u[j] = 0;
    }
    acc = __builtin_amdgcn_mfma_f32_16x16x32_bf16(af, bb.v, acc, 0, 0, 0);
  }

  if (il < 10) {
    float bias = ob[m * 10 + il];
#pragma unroll
    for (int r = 0; r < 4; ++r)
      out[(size_t)(b0 + q * 4 + r) * 800 + m * 10 + il] = acc[r] + bias;
  }
}

extern "C" void kernel_launch(void* const* d_in, const int* in_sizes, int n_in,
                              void* d_out, int out_size, void* d_ws, size_t ws_size,
                              hipStream_t stream) {
  const float* x = (const float*)d_in[0];
  const float* hw = (const float*)d_in[1];
  const float* hb = (const float*)d_in[2];
  const float* ow = (const float*)d_in[3];
  const float* ob = (const float*)d_in[4];
  float* out = (float*)d_out;

  // workspace layout: x_bf16 (1 MB) | w_bf16 (19.66 MB) | a_bf16 (39.32 MB)
  char* ws = (char*)d_ws;
  u16* xb = (u16*)ws;
  u16* wb = (u16*)(ws + 1048576);
  u16* ab = (u16*)(ws + 1048576 + 19660800);

  const int nx4 = (1024 * 512) / 4;    // 131072
  const int nw4 = (19200 * 512) / 4;   // 2457600
  const int tot = nx4 + nw4;           // 2588672 = 10112*256
  cvt_kernel<<<tot / 256, 256, 0, stream>>>((const float4*)x, (uint2*)xb, nx4,
                                            (const float4*)hw, (uint2*)wb, nw4);
  gemm_act_kernel<<<1200, 256, 0, stream>>>(xb, wb, hb, ab);
  layer2_kernel<<<1280, 256, 0, stream>>>(ab, ow, ob, out);
}